// Round 10
// baseline (396.610 us; speedup 1.0000x reference)
//
#include <hip/hip_runtime.h>
#include <hip/hip_bf16.h>

// STSA R10: R7 (known-good, 155us) + wave-sliced coalesced KV gather layout.
//  k_prep    : weights -> bf16.                              (unchanged)
//  k_fused_t : per (b,m): x->regs, 6 projections, temporal attn -> ot.
//              sk/sv now stored wave-slice-chunk-major: dim-slice w'=d>>5,
//              block (w'*1024+bm) of 4KB = [key t][quarter q][8 bf16].
//  k_attn_s  : R7 structure exactly (zero-barrier wave-private, reg prefetch,
//              scalar-V reads); ISSUE now reads 4 x 1KB CONTIGUOUS per wave;
//              WRITEKV redistributes: lane l holds quarter q=l&3 of key
//              kk=s*16+(l>>2); K slot = (l&3)^((l>>2)&3)^(l>>4) so the
//              unchanged R7 reader finds quarter (2hh+hi1) of row at
//              slot ((2hh+hi1)^xr(row)).
//  k_comb    : outproj(ot)+outproj(os)+bias -> out.          (unchanged)
// Softmax scale folded into Q (0.25*log2e*0.5; 0.5 compensates hd=16 duplicated
// into both K-halves), exp2, no max-subtract, normalize at the end.

typedef __attribute__((ext_vector_type(8))) short bf16x8;
typedef __attribute__((ext_vector_type(4))) short short4v;
typedef __attribute__((ext_vector_type(4))) float f32x4;

#define DEVI static __device__ __forceinline__
#define MFMA(a, b, c) __builtin_amdgcn_mfma_f32_16x16x32_bf16(a, b, c, 0, 0, 0)

static constexpr float QSCALE = 0.25f * 1.44269504088896340736f * 0.5f;

DEVI short f2bfs(float f) {
  __hip_bfloat16 h = __float2bfloat16(f);
  return __builtin_bit_cast(short, h);
}

// 64 rows x 128 bf16 LDS tile, 256B rows, XOR swizzle on write AND read.
DEVI int swzb(int row, int colh) {
  return (row * 256 + colh * 2) ^ ((row & 7) << 4);
}

// ---------------------------------------------------------------- k_prep ----
__global__ void __launch_bounds__(256) k_prep(
    const float* __restrict__ twin, const float* __restrict__ tbin,
    const float* __restrict__ twout, const float* __restrict__ tbout,
    const float* __restrict__ swin, const float* __restrict__ sbin,
    const float* __restrict__ swout, const float* __restrict__ sbout,
    short* __restrict__ wcat, float* __restrict__ biasin,
    short* __restrict__ wto, short* __restrict__ wso, float* __restrict__ biasc) {
  const int stride = gridDim.x * 256;
  const int t0 = blockIdx.x * 256 + threadIdx.x;
  for (int i = t0; i < 768 * 128; i += stride) {
    float v = (i < 384 * 128) ? twin[i] : swin[i - 384 * 128];
    wcat[i] = f2bfs(v);
  }
  for (int i = t0; i < 128 * 128; i += stride) {
    wto[i] = f2bfs(twout[i]);
    wso[i] = f2bfs(swout[i]);
  }
  for (int i = t0; i < 768; i += stride)
    biasin[i] = (i < 384) ? tbin[i] : sbin[i - 384];
  for (int i = t0; i < 128; i += stride)
    biasc[i] = tbout[i] + sbout[i];
}

// --------------------------------------------------------------- helpers ----
DEVI void attn_block(const char* qbuf, const char* kbuf, const char* vbuf,
                     int w, int lo, int hi, int colq,
                     f32x4 (*o)[4], float (*ls)[4]) {
  const f32x4 zf = {0.f, 0.f, 0.f, 0.f};
#pragma unroll
  for (int hh = 0; hh < 2; ++hh) {
    const int hc = (2 * w + hh) * 16;
    bf16x8 qf[4];
#pragma unroll
    for (int qt = 0; qt < 4; ++qt)
      qf[qt] = *(const bf16x8*)(qbuf + swzb(16 * qt + lo, hc + colq));
#pragma unroll
    for (int kc = 0; kc < 2; ++kc) {
      bf16x8 kf0 = *(const bf16x8*)(kbuf + swzb(16 * (2 * kc) + lo, hc + colq));
      bf16x8 kf1 = *(const bf16x8*)(kbuf + swzb(16 * (2 * kc + 1) + lo, hc + colq));
      f32x4 st0[4], st1[4];
#pragma unroll
      for (int qt = 0; qt < 4; ++qt) {
        st0[qt] = MFMA(kf0, qf[qt], zf);
        st1[qt] = MFMA(kf1, qf[qt], zf);
      }
#pragma unroll
      for (int qt = 0; qt < 4; ++qt)
#pragma unroll
        for (int r = 0; r < 4; ++r) {
          float p0 = exp2f(st0[qt][r]);
          float p1 = exp2f(st1[qt][r]);
          st0[qt][r] = p0; st1[qt][r] = p1;
          ls[hh][qt] += p0 + p1;
        }
      bf16x8 vf;
#pragma unroll
      for (int i = 0; i < 8; ++i) {
        int key = 32 * kc + 16 * (i >> 2) + 4 * hi + (i & 3);
        vf[i] = *(const short*)(vbuf + swzb(key, hc + lo));
      }
#pragma unroll
      for (int qt = 0; qt < 4; ++qt) {
        bf16x8 pa;
#pragma unroll
        for (int r = 0; r < 4; ++r) {
          pa[r] = f2bfs(st0[qt][r]);
          pa[4 + r] = f2bfs(st1[qt][r]);
        }
        o[hh][qt] = MFMA(pa, vf, o[hh][qt]);
      }
    }
  }
}

DEVI void outproj(const char* abuf, const short* __restrict__ wmat,
                  int w, int lo, int hi, f32x4* acc) {
#pragma unroll
  for (int kc = 0; kc < 4; ++kc) {
    bf16x8 a = *(const bf16x8*)(abuf + swzb(16 * w + lo, 32 * kc + 8 * hi));
#pragma unroll
    for (int ct = 0; ct < 8; ++ct) {
      bf16x8 bf = *(const bf16x8*)(wmat + (16 * ct + lo) * 128 + 32 * kc + 8 * hi);
      acc[ct] = MFMA(a, bf, acc[ct]);
    }
  }
}

// -------------------------------------------------------------- k_fused_t ----
__global__ void __launch_bounds__(256) k_fused_t(
    const float* __restrict__ x, const short* __restrict__ wcat,
    const float* __restrict__ biasin,
    short* __restrict__ sq, short* __restrict__ sk, short* __restrict__ sv,
    uint4* __restrict__ ot) {
  __shared__ uint4 smv[3072];  // 48 KiB
  char* bufX = (char*)smv;     // x -> t_v
  char* bufQ = bufX + 16384;   // t_q -> O_t stage
  char* bufK = bufX + 32768;   // t_k
  const int bm = blockIdx.x, b = bm >> 8, m = bm & 255;
  const int tid = threadIdx.x;

#pragma unroll
  for (int it = 0; it < 8; ++it) {
    int li = it * 256 + tid;
    int row = li >> 5, c4 = li & 31;
    float4 v = reinterpret_cast<const float4*>(x)[(size_t)((b * 64 + row) * 256 + m) * 32 + c4];
    short4v s;
    s[0] = f2bfs(v.x); s[1] = f2bfs(v.y); s[2] = f2bfs(v.z); s[3] = f2bfs(v.w);
    *(short4v*)(bufX + swzb(row, c4 * 4)) = s;
  }
  __syncthreads();

  const int w = tid >> 6, lane = tid & 63, lo = lane & 15, hi = lane >> 4;
  const int colq = 8 * (hi & 1);
  const f32x4 zf = {0.f, 0.f, 0.f, 0.f};

  bf16x8 af[4][4];
#pragma unroll
  for (int kc = 0; kc < 4; ++kc)
#pragma unroll
    for (int rt = 0; rt < 4; ++rt)
      af[kc][rt] = *(const bf16x8*)(bufX + swzb(16 * rt + lo, 32 * kc + 8 * hi));
  __syncthreads();

#pragma unroll
  for (int p = 0; p < 6; ++p) {
#pragma unroll
    for (int j = 0; j < 2; ++j) {
      int ct = 2 * w + j;
      f32x4 a4[4] = {zf, zf, zf, zf};
#pragma unroll
      for (int kc = 0; kc < 4; ++kc) {
        bf16x8 bcol = *(const bf16x8*)(wcat + (p * 128 + 16 * ct + lo) * 128 + 32 * kc + 8 * hi);
#pragma unroll
        for (int rt = 0; rt < 4; ++rt) a4[rt] = MFMA(af[kc][rt], bcol, a4[rt]);
      }
      float bb = biasin[p * 128 + 16 * ct + lo];
      if (p < 3) {
        char* pb = (p == 0) ? bufQ : (p == 1) ? bufK : bufX;
        float sc = (p == 0) ? QSCALE : 1.0f;
#pragma unroll
        for (int rt = 0; rt < 4; ++rt)
#pragma unroll
          for (int r = 0; r < 4; ++r)
            *(short*)(pb + swzb(16 * rt + 4 * hi + r, 16 * ct + lo)) =
                f2bfs((a4[rt][r] + bb) * sc);
      } else if (p == 3) {
#pragma unroll
        for (int rt = 0; rt < 4; ++rt)
#pragma unroll
          for (int r = 0; r < 4; ++r)
            sq[(size_t)(bm * 64 + 16 * rt + 4 * hi + r) * 128 + 16 * ct + lo] =
                f2bfs((a4[rt][r] + bb) * QSCALE);
      } else {
        // sk/sv wave-slice-chunk-major: block (w'*1024+bm), w' = (16ct+lo)>>5 = ct>>1
        // within block: t*32 shorts + q*8 + e;  q = (ct&1)*2 + (lo>>3), e = lo&7
        short* dst = (p == 4) ? sk : sv;
        size_t blk = ((size_t)((ct >> 1) * 1024 + bm)) * 2048;
        int qe = ((ct & 1) * 2 + (lo >> 3)) * 8 + (lo & 7);
#pragma unroll
        for (int rt = 0; rt < 4; ++rt)
#pragma unroll
          for (int r = 0; r < 4; ++r)
            dst[blk + (16 * rt + 4 * hi + r) * 32 + qe] = f2bfs(a4[rt][r] + bb);
      }
    }
  }
  __syncthreads();

  f32x4 o_t[2][4];
  float ls_t[2][4];
#pragma unroll
  for (int hh = 0; hh < 2; ++hh)
#pragma unroll
    for (int qt = 0; qt < 4; ++qt) { o_t[hh][qt] = zf; ls_t[hh][qt] = 0.f; }
  attn_block(bufQ, bufK, bufX, w, lo, hi, colq, o_t, ls_t);
  __syncthreads();

#pragma unroll
  for (int hh = 0; hh < 2; ++hh) {
    const int hc = (2 * w + hh) * 16;
#pragma unroll
    for (int qt = 0; qt < 4; ++qt) {
      float l = ls_t[hh][qt];
      l += __shfl_xor(l, 16);
      l += __shfl_xor(l, 32);
      float linv = 1.0f / l;
#pragma unroll
      for (int r = 0; r < 4; ++r) {
        float lr = __shfl(linv, 4 * hi + r);
        *(short*)(bufQ + swzb(16 * qt + 4 * hi + r, hc + lo)) = f2bfs(o_t[hh][qt][r] * lr);
      }
    }
  }
  __syncthreads();
#pragma unroll
  for (int it = 0; it < 4; ++it) {
    int li = it * 256 + tid;
    ot[(size_t)bm * 1024 + li] = *(const uint4*)(bufQ + swzb(li >> 4, (li & 15) * 8));
  }
}

// --------------------------------------------------------------- k_attn_s ----
// R7 structure. Wave w of block bm = head-pair w (dims w*32..w*32+32).
// Per-wave LDS 8KiB: K [64 key][4 x 16B xor-slots], V [64 key][32 dim].
// ISSUE: 4 x 1KB contiguous loads from wave-sliced sk/sv blocks.
// Lane l load s holds quarter q=l&3 of key kk=s*16+(l>>2).
// K write slot = (l&3) ^ ((l>>2)&3) ^ (l>>4)  [= q ^ xr(kk)].
// Reader (unchanged R7): slot ((2hh+hi1) ^ xr(row)), xr(row)=(row&3)^((row>>2)&3).
__global__ void __launch_bounds__(256, 3) k_attn_s(
    const short* __restrict__ sq, const short* __restrict__ skp,
    const short* __restrict__ svp, const int* __restrict__ route,
    short* __restrict__ os) {
  __shared__ char smem[32768];
  const int bm = blockIdx.x, b = bm >> 8, m = bm & 255;
  const int tid = threadIdx.x;
  const int w = tid >> 6, l = tid & 63;
  const int lo = l & 15, hi = l >> 4, hi1 = hi & 1;
  const int xr = (l & 3) ^ ((l >> 2) & 3);          // reader xor (f(lo), as R7)
  const int sw = (l & 3) ^ ((l >> 2) & 3) ^ (l >> 4);  // writer slot for key kk
  char* kbase = smem + w * 8192;
  char* vbase = kbase + 4096;
  const uint4* skp4 = (const uint4*)skp;
  const uint4* svp4 = (const uint4*)svp;
  const f32x4 zf = {0.f, 0.f, 0.f, 0.f};

  // Q fragments (this head-pair's 32-dim slice), loaded once from global
  bf16x8 qf[2][4];
#pragma unroll
  for (int hh = 0; hh < 2; ++hh)
#pragma unroll
    for (int qt = 0; qt < 4; ++qt)
      qf[hh][qt] = *(const bf16x8*)(sq + (size_t)(bm * 64 + 16 * qt + lo) * 128 +
                                    w * 32 + hh * 16 + 8 * hi1);

  uint4 pk[4], pv[4];
  int nb = route[m * 4 + 0];

#define ISSUE()                                                            \
  do {                                                                     \
    size_t base = ((size_t)(w * 1024 + b * 256 + nb)) * 256;               \
    _Pragma("unroll") for (int s = 0; s < 4; ++s) {                        \
      pk[s] = skp4[base + s * 64 + l];                                     \
      pv[s] = svp4[base + s * 64 + l];                                     \
    }                                                                      \
  } while (0)

#define WRITEKV()                                                          \
  do {                                                                     \
    _Pragma("unroll") for (int s = 0; s < 4; ++s) {                        \
      int kk = s * 16 + (l >> 2);                                          \
      *(uint4*)(kbase + kk * 64 + sw * 16) = pk[s];                        \
      *(uint4*)(vbase + kk * 64 + (l & 3) * 16) = pv[s];                   \
    }                                                                      \
  } while (0)

  ISSUE();
  WRITEKV();

  f32x4 o[2][4];
  float ls[2][4];
#pragma unroll
  for (int hh = 0; hh < 2; ++hh)
#pragma unroll
    for (int qt = 0; qt < 4; ++qt) { o[hh][qt] = zf; ls[hh][qt] = 0.f; }

#pragma unroll
  for (int c = 0; c < 4; ++c) {
    if (c < 3) { nb = route[m * 4 + c + 1]; ISSUE(); }  // prefetch next chunk
#pragma unroll
    for (int hh = 0; hh < 2; ++hh) {
      const int slotb = ((2 * hh + hi1) ^ xr) * 16;
      bf16x8 kf[4];
#pragma unroll
      for (int kt = 0; kt < 4; ++kt)
        kf[kt] = *(const bf16x8*)(kbase + (16 * kt + lo) * 64 + slotb);
#pragma unroll
      for (int kc = 0; kc < 2; ++kc) {
        f32x4 st0[4], st1[4];
#pragma unroll
        for (int qt = 0; qt < 4; ++qt) {
          st0[qt] = MFMA(kf[2 * kc], qf[hh][qt], zf);
          st1[qt] = MFMA(kf[2 * kc + 1], qf[hh][qt], zf);
        }
#pragma unroll
        for (int qt = 0; qt < 4; ++qt)
#pragma unroll
          for (int r = 0; r < 4; ++r) {
            float p0 = exp2f(st0[qt][r]);
            float p1 = exp2f(st1[qt][r]);
            st0[qt][r] = p0; st1[qt][r] = p1;
            ls[hh][qt] += p0 + p1;
          }
        // V fragments: 8 scalar reads, V[key][dim] rows (as R7)
        bf16x8 vf;
#pragma unroll
        for (int i = 0; i < 8; ++i) {
          int key = 32 * kc + 16 * (i >> 2) + 4 * hi + (i & 3);
          vf[i] = *(const short*)(vbase + key * 64 + (hh * 16 + lo) * 2);
        }
#pragma unroll
        for (int qt = 0; qt < 4; ++qt) {
          bf16x8 pa;
#pragma unroll
          for (int r = 0; r < 4; ++r) {
            pa[r] = f2bfs(st0[qt][r]);
            pa[4 + r] = f2bfs(st1[qt][r]);
          }
          o[hh][qt] = MFMA(pa, vf, o[hh][qt]);
        }
      }
    }
    if (c < 3) WRITEKV();  // after compute(c): same-wave DS order, no barrier
  }

  // normalize + stage O slice [64 q][32 dim] in kbase (wave-private), then store
#pragma unroll
  for (int hh = 0; hh < 2; ++hh)
#pragma unroll
    for (int qt = 0; qt < 4; ++qt) {
      float lsum = ls[hh][qt];
      lsum += __shfl_xor(lsum, 16);
      lsum += __shfl_xor(lsum, 32);
      float linv = 1.0f / lsum;
#pragma unroll
      for (int r = 0; r < 4; ++r) {
        float lr = __shfl(linv, 4 * hi + r);
        *(short*)(kbase + (16 * qt + 4 * hi + r) * 64 + (hh * 16 + lo) * 2) =
            f2bfs(o[hh][qt][r] * lr);
      }
    }
#pragma unroll
  for (int s = 0; s < 4; ++s) {
    uint4 u = *(const uint4*)(kbase + l * 64 + s * 16);
    ((uint4*)os)[((size_t)(bm * 64 + l) * 128 + w * 32) / 8 + s] = u;
  }
#undef ISSUE
#undef WRITEKV
}

// ----------------------------------------------------------------- k_comb ----
__global__ void __launch_bounds__(256) k_comb(
    const uint4* __restrict__ ot, const uint4* __restrict__ os,
    const short* __restrict__ wto, const short* __restrict__ wso,
    const float* __restrict__ biasc, float* __restrict__ out) {
  __shared__ uint4 smv[2048];  // 32 KiB
  char* bufT = (char*)smv;
  char* bufS = bufT + 16384;
  const int bm = blockIdx.x, b = bm >> 8, m = bm & 255;
  const int tid = threadIdx.x;
#pragma unroll
  for (int it = 0; it < 4; ++it) {
    int li = it * 256 + tid;
    int o_ = swzb(li >> 4, (li & 15) * 8);
    *(uint4*)(bufT + o_) = ot[(size_t)bm * 1024 + li];
    *(uint4*)(bufS + o_) = os[(size_t)bm * 1024 + li];
  }
  __syncthreads();
  const int w = tid >> 6, lane = tid & 63, lo = lane & 15, hi = lane >> 4;
  const f32x4 zf = {0.f, 0.f, 0.f, 0.f};
  f32x4 accT[8], accS[8];
#pragma unroll
  for (int ct = 0; ct < 8; ++ct) { accT[ct] = zf; accS[ct] = zf; }
  outproj(bufT, wto, w, lo, hi, accT);
  outproj(bufS, wso, w, lo, hi, accS);
#pragma unroll
  for (int ct = 0; ct < 8; ++ct) {
    float bb = biasc[16 * ct + lo];
#pragma unroll
    for (int r = 0; r < 4; ++r) {
      int t = 16 * w + 4 * hi + r;
      out[(size_t)((b * 64 + t) * 256 + m) * 128 + 16 * ct + lo] =
          accT[ct][r] + accS[ct][r] + bb;
    }
  }
}

// ---------------------------------------------------------------- launch ----
extern "C" void kernel_launch(void* const* d_in, const int* in_sizes, int n_in,
                              void* d_out, int out_size, void* d_ws, size_t ws_size,
                              hipStream_t stream) {
  (void)in_sizes; (void)n_in; (void)out_size; (void)ws_size;
  const float* x = (const float*)d_in[0];
  const int* route = (const int*)d_in[1];
  const float* twin = (const float*)d_in[2];
  const float* tbin = (const float*)d_in[3];
  const float* twout = (const float*)d_in[4];
  const float* tbout = (const float*)d_in[5];
  const float* swin = (const float*)d_in[6];
  const float* sbin = (const float*)d_in[7];
  const float* swout = (const float*)d_in[8];
  const float* sbout = (const float*)d_in[9];

  char* ws = (char*)d_ws;
  size_t off = 0;
  auto alloc = [&](size_t bytes) {
    char* p = ws + off;
    off += (bytes + 255) & ~(size_t)255;
    return p;
  };
  short* wcat = (short*)alloc(768 * 128 * 2);
  float* biasin = (float*)alloc(768 * 4);
  short* wto = (short*)alloc(128 * 128 * 2);
  short* wso = (short*)alloc(128 * 128 * 2);
  float* biasc = (float*)alloc(128 * 4);
  short* sq = (short*)alloc((size_t)65536 * 128 * 2);
  short* sk = (short*)alloc((size_t)65536 * 128 * 2);
  short* sv = (short*)alloc((size_t)65536 * 128 * 2);
  uint4* ot = (uint4*)alloc((size_t)65536 * 128 * 2);
  short* os = (short*)alloc((size_t)65536 * 128 * 2);
  float* out = (float*)d_out;

  k_prep<<<dim3(64), dim3(256), 0, stream>>>(twin, tbin, twout, tbout, swin, sbin,
                                             swout, sbout, wcat, biasin, wto, wso, biasc);
  k_fused_t<<<dim3(1024), dim3(256), 0, stream>>>(x, wcat, biasin, sq, sk, sv, ot);
  k_attn_s<<<dim3(1024), dim3(256), 0, stream>>>(sq, sk, sv, route, os);
  k_comb<<<dim3(1024), dim3(256), 0, stream>>>(ot, (const uint4*)os, wto, wso, biasc, out);
}

// Round 11
// 151.531 us; speedup vs baseline: 2.6174x; 2.6174x over previous
//
#include <hip/hip_runtime.h>
#include <hip/hip_bf16.h>

// STSA R11: R7 control flow (NO unroll on chunk loop — R8/R9/R10's ~300us
// regressions were unroll-induced scratch spill: FETCH/WRITE ~280/435MB of
// scratch round-trip, identical across 3 different gather implementations)
// + R10's coalesced wave-sliced gather layout + cooperative os store.
//  k_prep    : weights -> bf16.
//  k_fused_t : per (b,m): x->regs, 6 projections, temporal attn -> ot.
//              sk/sv stored wave-slice-chunk-major (4KB contiguous per
//              (dim-slice, bm)): block (w'*1024+bm), [key t][quarter q][8 bf16].
//  k_attn_s  : 1024 blocks x 4 waves; wave = (bm, head-pair). Per-wave 8KiB:
//              K [64 key][4x16B xor-slots], V [64 key][32 dim]. 4 neighbor
//              chunks, reg prefetch (ISSUE c+1 -> compute c -> WRITEKV c+1),
//              plain rolled loop, no mid-kernel barriers; final barrier +
//              block-coop full-line os store.
//  k_comb    : outproj(ot)+outproj(os)+bias -> out.
// Softmax scale folded into Q (0.25*log2e*0.5; 0.5 compensates hd=16 dup
// into both K-halves), exp2, no max-subtract, normalize at the end.

typedef __attribute__((ext_vector_type(8))) short bf16x8;
typedef __attribute__((ext_vector_type(4))) short short4v;
typedef __attribute__((ext_vector_type(4))) float f32x4;

#define DEVI static __device__ __forceinline__
#define MFMA(a, b, c) __builtin_amdgcn_mfma_f32_16x16x32_bf16(a, b, c, 0, 0, 0)

static constexpr float QSCALE = 0.25f * 1.44269504088896340736f * 0.5f;

DEVI short f2bfs(float f) {
  __hip_bfloat16 h = __float2bfloat16(f);
  return __builtin_bit_cast(short, h);
}

// 64 rows x 128 bf16 LDS tile, 256B rows, XOR swizzle on write AND read.
DEVI int swzb(int row, int colh) {
  return (row * 256 + colh * 2) ^ ((row & 7) << 4);
}

// ---------------------------------------------------------------- k_prep ----
__global__ void __launch_bounds__(256) k_prep(
    const float* __restrict__ twin, const float* __restrict__ tbin,
    const float* __restrict__ twout, const float* __restrict__ tbout,
    const float* __restrict__ swin, const float* __restrict__ sbin,
    const float* __restrict__ swout, const float* __restrict__ sbout,
    short* __restrict__ wcat, float* __restrict__ biasin,
    short* __restrict__ wto, short* __restrict__ wso, float* __restrict__ biasc) {
  const int stride = gridDim.x * 256;
  const int t0 = blockIdx.x * 256 + threadIdx.x;
  for (int i = t0; i < 768 * 128; i += stride) {
    float v = (i < 384 * 128) ? twin[i] : swin[i - 384 * 128];
    wcat[i] = f2bfs(v);
  }
  for (int i = t0; i < 128 * 128; i += stride) {
    wto[i] = f2bfs(twout[i]);
    wso[i] = f2bfs(swout[i]);
  }
  for (int i = t0; i < 768; i += stride)
    biasin[i] = (i < 384) ? tbin[i] : sbin[i - 384];
  for (int i = t0; i < 128; i += stride)
    biasc[i] = tbout[i] + sbout[i];
}

// --------------------------------------------------------------- helpers ----
DEVI void attn_block(const char* qbuf, const char* kbuf, const char* vbuf,
                     int w, int lo, int hi, int colq,
                     f32x4 (*o)[4], float (*ls)[4]) {
  const f32x4 zf = {0.f, 0.f, 0.f, 0.f};
#pragma unroll
  for (int hh = 0; hh < 2; ++hh) {
    const int hc = (2 * w + hh) * 16;
    bf16x8 qf[4];
#pragma unroll
    for (int qt = 0; qt < 4; ++qt)
      qf[qt] = *(const bf16x8*)(qbuf + swzb(16 * qt + lo, hc + colq));
#pragma unroll
    for (int kc = 0; kc < 2; ++kc) {
      bf16x8 kf0 = *(const bf16x8*)(kbuf + swzb(16 * (2 * kc) + lo, hc + colq));
      bf16x8 kf1 = *(const bf16x8*)(kbuf + swzb(16 * (2 * kc + 1) + lo, hc + colq));
      f32x4 st0[4], st1[4];
#pragma unroll
      for (int qt = 0; qt < 4; ++qt) {
        st0[qt] = MFMA(kf0, qf[qt], zf);
        st1[qt] = MFMA(kf1, qf[qt], zf);
      }
#pragma unroll
      for (int qt = 0; qt < 4; ++qt)
#pragma unroll
        for (int r = 0; r < 4; ++r) {
          float p0 = exp2f(st0[qt][r]);
          float p1 = exp2f(st1[qt][r]);
          st0[qt][r] = p0; st1[qt][r] = p1;
          ls[hh][qt] += p0 + p1;
        }
      bf16x8 vf;
#pragma unroll
      for (int i = 0; i < 8; ++i) {
        int key = 32 * kc + 16 * (i >> 2) + 4 * hi + (i & 3);
        vf[i] = *(const short*)(vbuf + swzb(key, hc + lo));
      }
#pragma unroll
      for (int qt = 0; qt < 4; ++qt) {
        bf16x8 pa;
#pragma unroll
        for (int r = 0; r < 4; ++r) {
          pa[r] = f2bfs(st0[qt][r]);
          pa[4 + r] = f2bfs(st1[qt][r]);
        }
        o[hh][qt] = MFMA(pa, vf, o[hh][qt]);
      }
    }
  }
}

DEVI void outproj(const char* abuf, const short* __restrict__ wmat,
                  int w, int lo, int hi, f32x4* acc) {
#pragma unroll
  for (int kc = 0; kc < 4; ++kc) {
    bf16x8 a = *(const bf16x8*)(abuf + swzb(16 * w + lo, 32 * kc + 8 * hi));
#pragma unroll
    for (int ct = 0; ct < 8; ++ct) {
      bf16x8 bf = *(const bf16x8*)(wmat + (16 * ct + lo) * 128 + 32 * kc + 8 * hi);
      acc[ct] = MFMA(a, bf, acc[ct]);
    }
  }
}

// -------------------------------------------------------------- k_fused_t ----
__global__ void __launch_bounds__(256) k_fused_t(
    const float* __restrict__ x, const short* __restrict__ wcat,
    const float* __restrict__ biasin,
    short* __restrict__ sq, short* __restrict__ sk, short* __restrict__ sv,
    uint4* __restrict__ ot) {
  __shared__ uint4 smv[3072];  // 48 KiB
  char* bufX = (char*)smv;     // x -> t_v
  char* bufQ = bufX + 16384;   // t_q -> O_t stage
  char* bufK = bufX + 32768;   // t_k
  const int bm = blockIdx.x, b = bm >> 8, m = bm & 255;
  const int tid = threadIdx.x;

#pragma unroll
  for (int it = 0; it < 8; ++it) {
    int li = it * 256 + tid;
    int row = li >> 5, c4 = li & 31;
    float4 v = reinterpret_cast<const float4*>(x)[(size_t)((b * 64 + row) * 256 + m) * 32 + c4];
    short4v s;
    s[0] = f2bfs(v.x); s[1] = f2bfs(v.y); s[2] = f2bfs(v.z); s[3] = f2bfs(v.w);
    *(short4v*)(bufX + swzb(row, c4 * 4)) = s;
  }
  __syncthreads();

  const int w = tid >> 6, lane = tid & 63, lo = lane & 15, hi = lane >> 4;
  const int colq = 8 * (hi & 1);
  const f32x4 zf = {0.f, 0.f, 0.f, 0.f};

  bf16x8 af[4][4];
#pragma unroll
  for (int kc = 0; kc < 4; ++kc)
#pragma unroll
    for (int rt = 0; rt < 4; ++rt)
      af[kc][rt] = *(const bf16x8*)(bufX + swzb(16 * rt + lo, 32 * kc + 8 * hi));
  __syncthreads();

#pragma unroll
  for (int p = 0; p < 6; ++p) {
#pragma unroll
    for (int j = 0; j < 2; ++j) {
      int ct = 2 * w + j;
      f32x4 a4[4] = {zf, zf, zf, zf};
#pragma unroll
      for (int kc = 0; kc < 4; ++kc) {
        bf16x8 bcol = *(const bf16x8*)(wcat + (p * 128 + 16 * ct + lo) * 128 + 32 * kc + 8 * hi);
#pragma unroll
        for (int rt = 0; rt < 4; ++rt) a4[rt] = MFMA(af[kc][rt], bcol, a4[rt]);
      }
      float bb = biasin[p * 128 + 16 * ct + lo];
      if (p < 3) {
        char* pb = (p == 0) ? bufQ : (p == 1) ? bufK : bufX;
        float sc = (p == 0) ? QSCALE : 1.0f;
#pragma unroll
        for (int rt = 0; rt < 4; ++rt)
#pragma unroll
          for (int r = 0; r < 4; ++r)
            *(short*)(pb + swzb(16 * rt + 4 * hi + r, 16 * ct + lo)) =
                f2bfs((a4[rt][r] + bb) * sc);
      } else if (p == 3) {
#pragma unroll
        for (int rt = 0; rt < 4; ++rt)
#pragma unroll
          for (int r = 0; r < 4; ++r)
            sq[(size_t)(bm * 64 + 16 * rt + 4 * hi + r) * 128 + 16 * ct + lo] =
                f2bfs((a4[rt][r] + bb) * QSCALE);
      } else {
        // sk/sv wave-slice-chunk-major: block (w'*1024+bm), w' = ct>>1
        // within block: t*32 shorts + q*8 + e;  q = (ct&1)*2 + (lo>>3), e = lo&7
        short* dst = (p == 4) ? sk : sv;
        size_t blk = ((size_t)((ct >> 1) * 1024 + bm)) * 2048;
        int qe = ((ct & 1) * 2 + (lo >> 3)) * 8 + (lo & 7);
#pragma unroll
        for (int rt = 0; rt < 4; ++rt)
#pragma unroll
          for (int r = 0; r < 4; ++r)
            dst[blk + (16 * rt + 4 * hi + r) * 32 + qe] = f2bfs(a4[rt][r] + bb);
      }
    }
  }
  __syncthreads();

  f32x4 o_t[2][4];
  float ls_t[2][4];
#pragma unroll
  for (int hh = 0; hh < 2; ++hh)
#pragma unroll
    for (int qt = 0; qt < 4; ++qt) { o_t[hh][qt] = zf; ls_t[hh][qt] = 0.f; }
  attn_block(bufQ, bufK, bufX, w, lo, hi, colq, o_t, ls_t);
  __syncthreads();

#pragma unroll
  for (int hh = 0; hh < 2; ++hh) {
    const int hc = (2 * w + hh) * 16;
#pragma unroll
    for (int qt = 0; qt < 4; ++qt) {
      float l = ls_t[hh][qt];
      l += __shfl_xor(l, 16);
      l += __shfl_xor(l, 32);
      float linv = 1.0f / l;
#pragma unroll
      for (int r = 0; r < 4; ++r) {
        float lr = __shfl(linv, 4 * hi + r);
        *(short*)(bufQ + swzb(16 * qt + 4 * hi + r, hc + lo)) = f2bfs(o_t[hh][qt][r] * lr);
      }
    }
  }
  __syncthreads();
#pragma unroll
  for (int it = 0; it < 4; ++it) {
    int li = it * 256 + tid;
    ot[(size_t)bm * 1024 + li] = *(const uint4*)(bufQ + swzb(li >> 4, (li & 15) * 8));
  }
}

// --------------------------------------------------------------- k_attn_s ----
// R7 control flow (rolled chunk loop!). Wave w of block bm = head-pair w.
// Per-wave LDS 8KiB: K [64 key][4 x 16B xor-slots], V [64 key][32 dim].
// ISSUE: 4 x 1KB contiguous loads from wave-sliced sk/sv blocks; lane l
// load s holds quarter q=l&3 of key kk=s*16+(l>>2).
// K write slot = (l&3)^((l>>2)&3)^(l>>4) = q ^ xr(kk); reader unchanged:
// slot ((2hh+hi1) ^ xr(row)), xr(row)=(row&3)^((row>>2)&3).
__global__ void __launch_bounds__(256, 3) k_attn_s(
    const short* __restrict__ sq, const short* __restrict__ skp,
    const short* __restrict__ svp, const int* __restrict__ route,
    short* __restrict__ os) {
  __shared__ char smem[32768];
  const int bm = blockIdx.x, b = bm >> 8, m = bm & 255;
  const int tid = threadIdx.x;
  const int w = tid >> 6, l = tid & 63;
  const int lo = l & 15, hi = l >> 4, hi1 = hi & 1;
  const int xr = (l & 3) ^ ((l >> 2) & 3);             // reader xor (f(lo))
  const int sw = (l & 3) ^ ((l >> 2) & 3) ^ (l >> 4);  // writer slot q^xr(kk)
  char* kbase = smem + w * 8192;
  char* vbase = kbase + 4096;
  const uint4* skp4 = (const uint4*)skp;
  const uint4* svp4 = (const uint4*)svp;
  const f32x4 zf = {0.f, 0.f, 0.f, 0.f};

  // Q fragments (this head-pair's 32-dim slice), loaded once from global
  bf16x8 qf[2][4];
#pragma unroll
  for (int hh = 0; hh < 2; ++hh)
#pragma unroll
    for (int qt = 0; qt < 4; ++qt)
      qf[hh][qt] = *(const bf16x8*)(sq + (size_t)(bm * 64 + 16 * qt + lo) * 128 +
                                    w * 32 + hh * 16 + 8 * hi1);

  uint4 pk[4], pv[4];
  int nb = route[m * 4 + 0];

#define ISSUE()                                                            \
  do {                                                                     \
    size_t base = ((size_t)(w * 1024 + b * 256 + nb)) * 256;               \
    _Pragma("unroll") for (int s = 0; s < 4; ++s) {                        \
      pk[s] = skp4[base + s * 64 + l];                                     \
      pv[s] = svp4[base + s * 64 + l];                                     \
    }                                                                      \
  } while (0)

#define WRITEKV()                                                          \
  do {                                                                     \
    _Pragma("unroll") for (int s = 0; s < 4; ++s) {                        \
      int kk = s * 16 + (l >> 2);                                          \
      *(uint4*)(kbase + kk * 64 + sw * 16) = pk[s];                        \
      *(uint4*)(vbase + kk * 64 + (l & 3) * 16) = pv[s];                   \
    }                                                                      \
  } while (0)

  ISSUE();
  WRITEKV();

  f32x4 o[2][4];
  float ls[2][4];
#pragma unroll
  for (int hh = 0; hh < 2; ++hh)
#pragma unroll
    for (int qt = 0; qt < 4; ++qt) { o[hh][qt] = zf; ls[hh][qt] = 0.f; }

  for (int c = 0; c < 4; ++c) {  // ROLLED — do not unroll (spill trigger)
    if (c < 3) { nb = route[m * 4 + c + 1]; ISSUE(); }  // prefetch next chunk
#pragma unroll
    for (int hh = 0; hh < 2; ++hh) {
      const int slotb = ((2 * hh + hi1) ^ xr) * 16;
      bf16x8 kf[4];
#pragma unroll
      for (int kt = 0; kt < 4; ++kt)
        kf[kt] = *(const bf16x8*)(kbase + (16 * kt + lo) * 64 + slotb);
#pragma unroll
      for (int kc = 0; kc < 2; ++kc) {
        f32x4 st0[4], st1[4];
#pragma unroll
        for (int qt = 0; qt < 4; ++qt) {
          st0[qt] = MFMA(kf[2 * kc], qf[hh][qt], zf);
          st1[qt] = MFMA(kf[2 * kc + 1], qf[hh][qt], zf);
        }
#pragma unroll
        for (int qt = 0; qt < 4; ++qt)
#pragma unroll
          for (int r = 0; r < 4; ++r) {
            float p0 = exp2f(st0[qt][r]);
            float p1 = exp2f(st1[qt][r]);
            st0[qt][r] = p0; st1[qt][r] = p1;
            ls[hh][qt] += p0 + p1;
          }
        // V fragments: 8 scalar reads, V[key][dim] rows (as R7)
        bf16x8 vf;
#pragma unroll
        for (int i = 0; i < 8; ++i) {
          int key = 32 * kc + 16 * (i >> 2) + 4 * hi + (i & 3);
          vf[i] = *(const short*)(vbase + key * 64 + (hh * 16 + lo) * 2);
        }
#pragma unroll
        for (int qt = 0; qt < 4; ++qt) {
          bf16x8 pa;
#pragma unroll
          for (int r = 0; r < 4; ++r) {
            pa[r] = f2bfs(st0[qt][r]);
            pa[4 + r] = f2bfs(st1[qt][r]);
          }
          o[hh][qt] = MFMA(pa, vf, o[hh][qt]);
        }
      }
    }
    if (c < 3) WRITEKV();  // after compute(c): same-wave DS order, no barrier
  }

  // normalize + stage O slice [64 q][32 dim] in kbase (wave-private)
#pragma unroll
  for (int hh = 0; hh < 2; ++hh)
#pragma unroll
    for (int qt = 0; qt < 4; ++qt) {
      float lsum = ls[hh][qt];
      lsum += __shfl_xor(lsum, 16);
      lsum += __shfl_xor(lsum, 32);
      float linv = 1.0f / lsum;
#pragma unroll
      for (int r = 0; r < 4; ++r) {
        float lr = __shfl(linv, 4 * hi + r);
        *(short*)(kbase + (16 * qt + 4 * hi + r) * 64 + (hh * 16 + lo) * 2) =
            f2bfs(o[hh][qt][r] * lr);
      }
    }
  __syncthreads();  // all waves staged -> block-coop full-line store
#pragma unroll
  for (int it = 0; it < 4; ++it) {
    int li = it * 256 + tid;
    int row = li >> 4, q16 = li & 15;
    const char* src = smem + (q16 >> 2) * 8192 + row * 64 + (q16 & 3) * 16;
    ((uint4*)os)[(size_t)bm * 1024 + li] = *(const uint4*)src;
  }
#undef ISSUE
#undef WRITEKV
}

// ----------------------------------------------------------------- k_comb ----
__global__ void __launch_bounds__(256) k_comb(
    const uint4* __restrict__ ot, const uint4* __restrict__ os,
    const short* __restrict__ wto, const short* __restrict__ wso,
    const float* __restrict__ biasc, float* __restrict__ out) {
  __shared__ uint4 smv[2048];  // 32 KiB
  char* bufT = (char*)smv;
  char* bufS = bufT + 16384;
  const int bm = blockIdx.x, b = bm >> 8, m = bm & 255;
  const int tid = threadIdx.x;
#pragma unroll
  for (int it = 0; it < 4; ++it) {
    int li = it * 256 + tid;
    int o_ = swzb(li >> 4, (li & 15) * 8);
    *(uint4*)(bufT + o_) = ot[(size_t)bm * 1024 + li];
    *(uint4*)(bufS + o_) = os[(size_t)bm * 1024 + li];
  }
  __syncthreads();
  const int w = tid >> 6, lane = tid & 63, lo = lane & 15, hi = lane >> 4;
  const f32x4 zf = {0.f, 0.f, 0.f, 0.f};
  f32x4 accT[8], accS[8];
#pragma unroll
  for (int ct = 0; ct < 8; ++ct) { accT[ct] = zf; accS[ct] = zf; }
  outproj(bufT, wto, w, lo, hi, accT);
  outproj(bufS, wso, w, lo, hi, accS);
#pragma unroll
  for (int ct = 0; ct < 8; ++ct) {
    float bb = biasc[16 * ct + lo];
#pragma unroll
    for (int r = 0; r < 4; ++r) {
      int t = 16 * w + 4 * hi + r;
      out[(size_t)((b * 64 + t) * 256 + m) * 128 + 16 * ct + lo] =
          accT[ct][r] + accS[ct][r] + bb;
    }
  }
}

// ---------------------------------------------------------------- launch ----
extern "C" void kernel_launch(void* const* d_in, const int* in_sizes, int n_in,
                              void* d_out, int out_size, void* d_ws, size_t ws_size,
                              hipStream_t stream) {
  (void)in_sizes; (void)n_in; (void)out_size; (void)ws_size;
  const float* x = (const float*)d_in[0];
  const int* route = (const int*)d_in[1];
  const float* twin = (const float*)d_in[2];
  const float* tbin = (const float*)d_in[3];
  const float* twout = (const float*)d_in[4];
  const float* tbout = (const float*)d_in[5];
  const float* swin = (const float*)d_in[6];
  const float* sbin = (const float*)d_in[7];
  const float* swout = (const float*)d_in[8];
  const float* sbout = (const float*)d_in[9];

  char* ws = (char*)d_ws;
  size_t off = 0;
  auto alloc = [&](size_t bytes) {
    char* p = ws + off;
    off += (bytes + 255) & ~(size_t)255;
    return p;
  };
  short* wcat = (short*)alloc(768 * 128 * 2);
  float* biasin = (float*)alloc(768 * 4);
  short* wto = (short*)alloc(128 * 128 * 2);
  short* wso = (short*)alloc(128 * 128 * 2);
  float* biasc = (float*)alloc(128 * 4);
  short* sq = (short*)alloc((size_t)65536 * 128 * 2);
  short* sk = (short*)alloc((size_t)65536 * 128 * 2);
  short* sv = (short*)alloc((size_t)65536 * 128 * 2);
  uint4* ot = (uint4*)alloc((size_t)65536 * 128 * 2);
  short* os = (short*)alloc((size_t)65536 * 128 * 2);
  float* out = (float*)d_out;

  k_prep<<<dim3(64), dim3(256), 0, stream>>>(twin, tbin, twout, tbout, swin, sbin,
                                             swout, sbout, wcat, biasin, wto, wso, biasc);
  k_fused_t<<<dim3(1024), dim3(256), 0, stream>>>(x, wcat, biasin, sq, sk, sv, ot);
  k_attn_s<<<dim3(1024), dim3(256), 0, stream>>>(sq, sk, sv, route, os);
  k_comb<<<dim3(1024), dim3(256), 0, stream>>>(ot, (const uint4*)os, wto, wso, biasc, out);
}

// Round 14
// 137.306 us; speedup vs baseline: 2.8885x; 1.1036x over previous
//
#include <hip/hip_runtime.h>
#include <hip/hip_bf16.h>

// STSA R14: R11 + fused out-proj tail + V stride 80.
// R12/R13 post-mortem: stride-72 V rows made adjacent u64 LDS stores mergeable
// into a 16B-alignment-requiring ds_write_b128 at 8-aligned addresses (odd keys)
// -> silent V corruption. Stride 80 = 5*16: every V write is ONE uint4 store at
// a 16B-aligned address (same instruction shape as passing R11), reads are u16;
// read conflicts drop 4-way -> 2-way (free).
//  k_prep    : weights -> bf16.
//  k_fused_t : per (b,m): x->regs, 6 projections, temporal attn -> ot (bf16).
//              sk/sv stored wave-slice-chunk-major (4KB contiguous per
//              (dim-slice, bm)): block (w'*1024+bm), [key t][quarter q][8 bf16].
//  k_attn_s  : 1024 blocks x 4 waves; wave = (bm, head-pair). Per-wave 9216B:
//              K [64 key][4x16B xor-slots] @0, V [64 key][80B-stride rows] @4096.
//              4 neighbor-chunks, reg prefetch, ROLLED chunk loop (unrolling
//              triggered R8-R10's scratch-spill regressions), no mid-loop
//              barriers. Tail: stage normalized O_s into K region (stride 64,
//              16B-aligned), one barrier, dual out-proj (O_s from LDS + O_t
//              from global ot) + bias -> single out write. No k_comb.
// Softmax scale folded into Q (0.25*log2e*0.5; 0.5 compensates hd=16 dup
// into both K-halves), exp2, no max-subtract, normalize at the end.

typedef __attribute__((ext_vector_type(8))) short bf16x8;
typedef __attribute__((ext_vector_type(4))) short short4v;
typedef __attribute__((ext_vector_type(4))) float f32x4;

#define DEVI static __device__ __forceinline__
#define MFMA(a, b, c) __builtin_amdgcn_mfma_f32_16x16x32_bf16(a, b, c, 0, 0, 0)

static constexpr float QSCALE = 0.25f * 1.44269504088896340736f * 0.5f;

DEVI short f2bfs(float f) {
  __hip_bfloat16 h = __float2bfloat16(f);
  return __builtin_bit_cast(short, h);
}

// 64 rows x 128 bf16 LDS tile, 256B rows, XOR swizzle on write AND read.
DEVI int swzb(int row, int colh) {
  return (row * 256 + colh * 2) ^ ((row & 7) << 4);
}

// ---------------------------------------------------------------- k_prep ----
__global__ void __launch_bounds__(256) k_prep(
    const float* __restrict__ twin, const float* __restrict__ tbin,
    const float* __restrict__ twout, const float* __restrict__ tbout,
    const float* __restrict__ swin, const float* __restrict__ sbin,
    const float* __restrict__ swout, const float* __restrict__ sbout,
    short* __restrict__ wcat, float* __restrict__ biasin,
    short* __restrict__ wto, short* __restrict__ wso, float* __restrict__ biasc) {
  const int stride = gridDim.x * 256;
  const int t0 = blockIdx.x * 256 + threadIdx.x;
  for (int i = t0; i < 768 * 128; i += stride) {
    float v = (i < 384 * 128) ? twin[i] : swin[i - 384 * 128];
    wcat[i] = f2bfs(v);
  }
  for (int i = t0; i < 128 * 128; i += stride) {
    wto[i] = f2bfs(twout[i]);
    wso[i] = f2bfs(swout[i]);
  }
  for (int i = t0; i < 768; i += stride)
    biasin[i] = (i < 384) ? tbin[i] : sbin[i - 384];
  for (int i = t0; i < 128; i += stride)
    biasc[i] = tbout[i] + sbout[i];
}

// --------------------------------------------------------------- helpers ----
DEVI void attn_block(const char* qbuf, const char* kbuf, const char* vbuf,
                     int w, int lo, int hi, int colq,
                     f32x4 (*o)[4], float (*ls)[4]) {
  const f32x4 zf = {0.f, 0.f, 0.f, 0.f};
#pragma unroll
  for (int hh = 0; hh < 2; ++hh) {
    const int hc = (2 * w + hh) * 16;
    bf16x8 qf[4];
#pragma unroll
    for (int qt = 0; qt < 4; ++qt)
      qf[qt] = *(const bf16x8*)(qbuf + swzb(16 * qt + lo, hc + colq));
#pragma unroll
    for (int kc = 0; kc < 2; ++kc) {
      bf16x8 kf0 = *(const bf16x8*)(kbuf + swzb(16 * (2 * kc) + lo, hc + colq));
      bf16x8 kf1 = *(const bf16x8*)(kbuf + swzb(16 * (2 * kc + 1) + lo, hc + colq));
      f32x4 st0[4], st1[4];
#pragma unroll
      for (int qt = 0; qt < 4; ++qt) {
        st0[qt] = MFMA(kf0, qf[qt], zf);
        st1[qt] = MFMA(kf1, qf[qt], zf);
      }
#pragma unroll
      for (int qt = 0; qt < 4; ++qt)
#pragma unroll
        for (int r = 0; r < 4; ++r) {
          float p0 = exp2f(st0[qt][r]);
          float p1 = exp2f(st1[qt][r]);
          st0[qt][r] = p0; st1[qt][r] = p1;
          ls[hh][qt] += p0 + p1;
        }
      bf16x8 vf;
#pragma unroll
      for (int i = 0; i < 8; ++i) {
        int key = 32 * kc + 16 * (i >> 2) + 4 * hi + (i & 3);
        vf[i] = *(const short*)(vbuf + swzb(key, hc + lo));
      }
#pragma unroll
      for (int qt = 0; qt < 4; ++qt) {
        bf16x8 pa;
#pragma unroll
        for (int r = 0; r < 4; ++r) {
          pa[r] = f2bfs(st0[qt][r]);
          pa[4 + r] = f2bfs(st1[qt][r]);
        }
        o[hh][qt] = MFMA(pa, vf, o[hh][qt]);
      }
    }
  }
}

// -------------------------------------------------------------- k_fused_t ----
__global__ void __launch_bounds__(256) k_fused_t(
    const float* __restrict__ x, const short* __restrict__ wcat,
    const float* __restrict__ biasin,
    short* __restrict__ sq, short* __restrict__ sk, short* __restrict__ sv,
    uint4* __restrict__ ot) {
  __shared__ uint4 smv[3072];  // 48 KiB
  char* bufX = (char*)smv;     // x -> t_v
  char* bufQ = bufX + 16384;   // t_q -> O_t stage
  char* bufK = bufX + 32768;   // t_k
  const int bm = blockIdx.x, b = bm >> 8, m = bm & 255;
  const int tid = threadIdx.x;

#pragma unroll
  for (int it = 0; it < 8; ++it) {
    int li = it * 256 + tid;
    int row = li >> 5, c4 = li & 31;
    float4 v = reinterpret_cast<const float4*>(x)[(size_t)((b * 64 + row) * 256 + m) * 32 + c4];
    short4v s;
    s[0] = f2bfs(v.x); s[1] = f2bfs(v.y); s[2] = f2bfs(v.z); s[3] = f2bfs(v.w);
    *(short4v*)(bufX + swzb(row, c4 * 4)) = s;
  }
  __syncthreads();

  const int w = tid >> 6, lane = tid & 63, lo = lane & 15, hi = lane >> 4;
  const int colq = 8 * (hi & 1);
  const f32x4 zf = {0.f, 0.f, 0.f, 0.f};

  bf16x8 af[4][4];
#pragma unroll
  for (int kc = 0; kc < 4; ++kc)
#pragma unroll
    for (int rt = 0; rt < 4; ++rt)
      af[kc][rt] = *(const bf16x8*)(bufX + swzb(16 * rt + lo, 32 * kc + 8 * hi));
  __syncthreads();

#pragma unroll
  for (int p = 0; p < 6; ++p) {
#pragma unroll
    for (int j = 0; j < 2; ++j) {
      int ct = 2 * w + j;
      f32x4 a4[4] = {zf, zf, zf, zf};
#pragma unroll
      for (int kc = 0; kc < 4; ++kc) {
        bf16x8 bcol = *(const bf16x8*)(wcat + (p * 128 + 16 * ct + lo) * 128 + 32 * kc + 8 * hi);
#pragma unroll
        for (int rt = 0; rt < 4; ++rt) a4[rt] = MFMA(af[kc][rt], bcol, a4[rt]);
      }
      float bb = biasin[p * 128 + 16 * ct + lo];
      if (p < 3) {
        char* pb = (p == 0) ? bufQ : (p == 1) ? bufK : bufX;
        float sc = (p == 0) ? QSCALE : 1.0f;
#pragma unroll
        for (int rt = 0; rt < 4; ++rt)
#pragma unroll
          for (int r = 0; r < 4; ++r)
            *(short*)(pb + swzb(16 * rt + 4 * hi + r, 16 * ct + lo)) =
                f2bfs((a4[rt][r] + bb) * sc);
      } else if (p == 3) {
#pragma unroll
        for (int rt = 0; rt < 4; ++rt)
#pragma unroll
          for (int r = 0; r < 4; ++r)
            sq[(size_t)(bm * 64 + 16 * rt + 4 * hi + r) * 128 + 16 * ct + lo] =
                f2bfs((a4[rt][r] + bb) * QSCALE);
      } else {
        // sk/sv wave-slice-chunk-major: block (w'*1024+bm), w' = ct>>1
        short* dst = (p == 4) ? sk : sv;
        size_t blk = ((size_t)((ct >> 1) * 1024 + bm)) * 2048;
        int qe = ((ct & 1) * 2 + (lo >> 3)) * 8 + (lo & 7);
#pragma unroll
        for (int rt = 0; rt < 4; ++rt)
#pragma unroll
          for (int r = 0; r < 4; ++r)
            dst[blk + (16 * rt + 4 * hi + r) * 32 + qe] = f2bfs(a4[rt][r] + bb);
      }
    }
  }
  __syncthreads();

  f32x4 o_t[2][4];
  float ls_t[2][4];
#pragma unroll
  for (int hh = 0; hh < 2; ++hh)
#pragma unroll
    for (int qt = 0; qt < 4; ++qt) { o_t[hh][qt] = zf; ls_t[hh][qt] = 0.f; }
  attn_block(bufQ, bufK, bufX, w, lo, hi, colq, o_t, ls_t);
  __syncthreads();

#pragma unroll
  for (int hh = 0; hh < 2; ++hh) {
    const int hc = (2 * w + hh) * 16;
#pragma unroll
    for (int qt = 0; qt < 4; ++qt) {
      float l = ls_t[hh][qt];
      l += __shfl_xor(l, 16);
      l += __shfl_xor(l, 32);
      float linv = 1.0f / l;
#pragma unroll
      for (int r = 0; r < 4; ++r) {
        float lr = __shfl(linv, 4 * hi + r);
        *(short*)(bufQ + swzb(16 * qt + 4 * hi + r, hc + lo)) = f2bfs(o_t[hh][qt][r] * lr);
      }
    }
  }
  __syncthreads();
#pragma unroll
  for (int it = 0; it < 4; ++it) {
    int li = it * 256 + tid;
    ot[(size_t)bm * 1024 + li] = *(const uint4*)(bufQ + swzb(li >> 4, (li & 15) * 8));
  }
}

// --------------------------------------------------------------- k_attn_s ----
// Wave w of block bm = head-pair w (dims w*32..w*32+32). Per-wave 9216B region:
//   K @0    : [64 key][4 x 16B slots], write slot = (l&3)^((l>>2)&3)^(l>>4),
//             read slot = ((2hh+hi1) ^ xr(row)), xr(row)=(row&3)^((row>>2)&3)
//   V @4096 : [64 key][80B-stride rows]; uint4 writes @16B-aligned (80=5*16,
//             stores 80B apart -> unmergeable), u16 reads 2-way (free)
// ISSUE: 4 x 1KB contiguous loads from wave-sliced sk/sv blocks; lane l load s
// holds quarter q=l&3 of key kk=s*16+(l>>2). Chunk loop ROLLED (spill guard).
// Tail: stage normalized O_s into K region (stride 64, 16B-aligned reads),
// barrier, dual out-proj (O_s from LDS, O_t from global ot) + bias -> out.
__global__ void __launch_bounds__(256, 3) k_attn_s(
    const short* __restrict__ sq, const short* __restrict__ skp,
    const short* __restrict__ svp, const int* __restrict__ route,
    const short* __restrict__ ot, const short* __restrict__ wto,
    const short* __restrict__ wso, const float* __restrict__ biasc,
    float* __restrict__ out) {
  __shared__ char smem[36864];  // 4 x 9216
  const int bm = blockIdx.x, b = bm >> 8, m = bm & 255;
  const int tid = threadIdx.x;
  const int w = tid >> 6, l = tid & 63;
  const int lo = l & 15, hi = l >> 4, hi1 = hi & 1;
  const int xr = (l & 3) ^ ((l >> 2) & 3);             // reader xor (f(lo))
  const int sw = (l & 3) ^ ((l >> 2) & 3) ^ (l >> 4);  // writer slot q^xr(kk)
  char* kbase = smem + w * 9216;
  char* vbase = kbase + 4096;
  const uint4* skp4 = (const uint4*)skp;
  const uint4* svp4 = (const uint4*)svp;
  const f32x4 zf = {0.f, 0.f, 0.f, 0.f};

  // Q fragments (this head-pair's 32-dim slice), loaded once from global
  bf16x8 qf[2][4];
#pragma unroll
  for (int hh = 0; hh < 2; ++hh)
#pragma unroll
    for (int qt = 0; qt < 4; ++qt)
      qf[hh][qt] = *(const bf16x8*)(sq + (size_t)(bm * 64 + 16 * qt + lo) * 128 +
                                    w * 32 + hh * 16 + 8 * hi1);

  uint4 pk[4], pv[4];
  int nb = route[m * 4 + 0];

#define ISSUE()                                                            \
  do {                                                                     \
    size_t base = ((size_t)(w * 1024 + b * 256 + nb)) * 256;               \
    _Pragma("unroll") for (int s = 0; s < 4; ++s) {                        \
      pk[s] = skp4[base + s * 64 + l];                                     \
      pv[s] = svp4[base + s * 64 + l];                                     \
    }                                                                      \
  } while (0)

#define WRITEKV()                                                          \
  do {                                                                     \
    _Pragma("unroll") for (int s = 0; s < 4; ++s) {                        \
      int kk = s * 16 + (l >> 2);                                          \
      *(uint4*)(kbase + kk * 64 + sw * 16) = pk[s];                        \
      *(uint4*)(vbase + kk * 80 + (l & 3) * 16) = pv[s];                   \
    }                                                                      \
  } while (0)

  ISSUE();
  WRITEKV();

  f32x4 o[2][4];
  float ls[2][4];
#pragma unroll
  for (int hh = 0; hh < 2; ++hh)
#pragma unroll
    for (int qt = 0; qt < 4; ++qt) { o[hh][qt] = zf; ls[hh][qt] = 0.f; }

  for (int c = 0; c < 4; ++c) {  // ROLLED — do not unroll (spill trigger)
    if (c < 3) { nb = route[m * 4 + c + 1]; ISSUE(); }  // prefetch next chunk
#pragma unroll
    for (int hh = 0; hh < 2; ++hh) {
      const int slotb = ((2 * hh + hi1) ^ xr) * 16;
      bf16x8 kf[4];
#pragma unroll
      for (int kt = 0; kt < 4; ++kt)
        kf[kt] = *(const bf16x8*)(kbase + (16 * kt + lo) * 64 + slotb);
#pragma unroll
      for (int kc = 0; kc < 2; ++kc) {
        f32x4 st0[4], st1[4];
#pragma unroll
        for (int qt = 0; qt < 4; ++qt) {
          st0[qt] = MFMA(kf[2 * kc], qf[hh][qt], zf);
          st1[qt] = MFMA(kf[2 * kc + 1], qf[hh][qt], zf);
        }
#pragma unroll
        for (int qt = 0; qt < 4; ++qt)
#pragma unroll
          for (int r = 0; r < 4; ++r) {
            float p0 = exp2f(st0[qt][r]);
            float p1 = exp2f(st1[qt][r]);
            st0[qt][r] = p0; st1[qt][r] = p1;
            ls[hh][qt] += p0 + p1;
          }
        // V fragments: 8 scalar u16 reads, [key][80B-stride] rows (2-way, free)
        bf16x8 vf;
#pragma unroll
        for (int i = 0; i < 8; ++i) {
          int key = 32 * kc + 16 * (i >> 2) + 4 * hi + (i & 3);
          vf[i] = *(const short*)(vbase + key * 80 + (hh * 16 + lo) * 2);
        }
#pragma unroll
        for (int qt = 0; qt < 4; ++qt) {
          bf16x8 pa;
#pragma unroll
          for (int r = 0; r < 4; ++r) {
            pa[r] = f2bfs(st0[qt][r]);
            pa[4 + r] = f2bfs(st1[qt][r]);
          }
          o[hh][qt] = MFMA(pa, vf, o[hh][qt]);
        }
      }
    }
    if (c < 3) WRITEKV();  // after compute(c): same-wave DS order, no barrier
  }

  // normalize + stage O_s [64 q][32 dim] into K region (stride 64; K dead)
#pragma unroll
  for (int hh = 0; hh < 2; ++hh)
#pragma unroll
    for (int qt = 0; qt < 4; ++qt) {
      float lsum = ls[hh][qt];
      lsum += __shfl_xor(lsum, 16);
      lsum += __shfl_xor(lsum, 32);
      float linv = 1.0f / lsum;
#pragma unroll
      for (int r = 0; r < 4; ++r) {
        float lr = __shfl(linv, 4 * hi + r);
        *(short*)(kbase + (16 * qt + 4 * hi + r) * 64 + (hh * 16 + lo) * 2) =
            f2bfs(o[hh][qt][r] * lr);
      }
    }
  __syncthreads();  // all waves staged

  // dual out-proj: accT from global ot fragments, accS from staged O_s (LDS)
  f32x4 accT[8], accS[8];
#pragma unroll
  for (int ct = 0; ct < 8; ++ct) { accT[ct] = zf; accS[ct] = zf; }
#pragma unroll
  for (int kc = 0; kc < 4; ++kc) {
    bf16x8 as = *(const bf16x8*)(smem + kc * 9216 + (16 * w + lo) * 64 + hi * 16);
    bf16x8 at = *(const bf16x8*)(ot + (size_t)bm * 8192 + (16 * w + lo) * 128 +
                                 32 * kc + 8 * hi);
#pragma unroll
    for (int ct = 0; ct < 8; ++ct) {
      bf16x8 bt = *(const bf16x8*)(wto + (16 * ct + lo) * 128 + 32 * kc + 8 * hi);
      bf16x8 bs = *(const bf16x8*)(wso + (16 * ct + lo) * 128 + 32 * kc + 8 * hi);
      accT[ct] = MFMA(at, bt, accT[ct]);
      accS[ct] = MFMA(as, bs, accS[ct]);
    }
  }
#pragma unroll
  for (int ct = 0; ct < 8; ++ct) {
    float bb = biasc[16 * ct + lo];
#pragma unroll
    for (int r = 0; r < 4; ++r) {
      int t = 16 * w + 4 * hi + r;
      out[(size_t)((b * 64 + t) * 256 + m) * 128 + 16 * ct + lo] =
          accT[ct][r] + accS[ct][r] + bb;
    }
  }
#undef ISSUE
#undef WRITEKV
}

// ---------------------------------------------------------------- launch ----
extern "C" void kernel_launch(void* const* d_in, const int* in_sizes, int n_in,
                              void* d_out, int out_size, void* d_ws, size_t ws_size,
                              hipStream_t stream) {
  (void)in_sizes; (void)n_in; (void)out_size; (void)ws_size;
  const float* x = (const float*)d_in[0];
  const int* route = (const int*)d_in[1];
  const float* twin = (const float*)d_in[2];
  const float* tbin = (const float*)d_in[3];
  const float* twout = (const float*)d_in[4];
  const float* tbout = (const float*)d_in[5];
  const float* swin = (const float*)d_in[6];
  const float* sbin = (const float*)d_in[7];
  const float* swout = (const float*)d_in[8];
  const float* sbout = (const float*)d_in[9];

  char* ws = (char*)d_ws;
  size_t off = 0;
  auto alloc = [&](size_t bytes) {
    char* p = ws + off;
    off += (bytes + 255) & ~(size_t)255;
    return p;
  };
  short* wcat = (short*)alloc(768 * 128 * 2);
  float* biasin = (float*)alloc(768 * 4);
  short* wto = (short*)alloc(128 * 128 * 2);
  short* wso = (short*)alloc(128 * 128 * 2);
  float* biasc = (float*)alloc(128 * 4);
  short* sq = (short*)alloc((size_t)65536 * 128 * 2);
  short* sk = (short*)alloc((size_t)65536 * 128 * 2);
  short* sv = (short*)alloc((size_t)65536 * 128 * 2);
  short* ot = (short*)alloc((size_t)65536 * 128 * 2);
  float* out = (float*)d_out;

  k_prep<<<dim3(64), dim3(256), 0, stream>>>(twin, tbin, twout, tbout, swin, sbin,
                                             swout, sbout, wcat, biasin, wto, wso, biasc);
  k_fused_t<<<dim3(1024), dim3(256), 0, stream>>>(x, wcat, biasin, sq, sk, sv,
                                                  (uint4*)ot);
  k_attn_s<<<dim3(1024), dim3(256), 0, stream>>>(sq, sk, sv, route, ot, wto, wso,
                                                 biasc, out);
}